// Round 1
// baseline (573.118 us; speedup 1.0000x reference)
//
#include <hip/hip_runtime.h>
#include <hip/hip_bf16.h>

#define NN 100000
#define EE 1600000
#define HH 8
#define CCH 16
#define HC 128
#define LN_EPS 1e-5f

// ---------------- K0: detect int64 vs int32 edge_index ----------------
__global__ void k_detect(const void* __restrict__ ei, int* __restrict__ flag) {
  if (threadIdx.x == 0 && blockIdx.x == 0) {
    const unsigned long long* p = (const unsigned long long*)ei;
    int ok = 1;
    for (int i = 0; i < 256; ++i)
      if (p[i] >= (unsigned long long)NN) { ok = 0; break; }
    *flag = ok;  // 1 => int64, 0 => int32
  }
}

// ---------------- K1: normalize edge_index to int32 ----------------
__global__ __launch_bounds__(256) void k_convert(const void* __restrict__ ei,
                                                 const int* __restrict__ flag,
                                                 int* __restrict__ idx32) {
  int i = blockIdx.x * 256 + threadIdx.x;
  if (i >= 2 * EE) return;
  if (*flag) idx32[i] = (int)((const long long*)ei)[i];
  else       idx32[i] = ((const int*)ei)[i];
}

// ---------------- K2: x = P@W, a_src, a_dst ----------------
// block = 512 (8 waves); wave w handles cols [w*16, w*16+16) == head w.
// lane l handles row rb + l. W read via wave-uniform (scalar) loads.
__global__ __launch_bounds__(512) void k_gemm_node(
    const float* __restrict__ P, const float* __restrict__ W,
    const float* __restrict__ attS, const float* __restrict__ attD,
    float* __restrict__ x, float* __restrict__ a_src, float* __restrict__ a_dst,
    int nrows) {
  __shared__ float Rl[32 * 66];  // [k][row], stride 66 -> conflict-free b32 reads
  int t = threadIdx.x;
  int w = __builtin_amdgcn_readfirstlane(t >> 6);
  int l = t & 63;
  int rb = blockIdx.x * 64;
  int cb = w * 16;
  float acc[16];
#pragma unroll
  for (int j = 0; j < 16; ++j) acc[j] = 0.f;

  for (int kc = 0; kc < 4; ++kc) {
    __syncthreads();
    {  // stage 64 rows x 32 k (transposed) : thread loads one float4
      int row = t >> 3;
      int k0 = (t & 7) * 4;
      int grow = rb + row;
      float4 v = make_float4(0.f, 0.f, 0.f, 0.f);
      if (grow < nrows)
        v = *(const float4*)(P + (size_t)grow * 128 + kc * 32 + k0);
      Rl[(k0 + 0) * 66 + row] = v.x;
      Rl[(k0 + 1) * 66 + row] = v.y;
      Rl[(k0 + 2) * 66 + row] = v.z;
      Rl[(k0 + 3) * 66 + row] = v.w;
    }
    __syncthreads();
    const float* Wp = W + (size_t)(kc * 32) * 128 + cb;
#pragma unroll 8
    for (int k = 0; k < 32; ++k) {
      float rv = Rl[k * 66 + l];
#pragma unroll
      for (int j = 0; j < 16; ++j) acc[j] = fmaf(rv, Wp[k * 128 + j], acc[j]);
    }
  }
  int row = rb + l;
  if (row < nrows) {
    float sa = 0.f, sd = 0.f;
#pragma unroll
    for (int j = 0; j < 16; ++j) {
      sa = fmaf(acc[j], attS[cb + j], sa);
      sd = fmaf(acc[j], attD[cb + j], sd);
    }
    a_src[row * 8 + w] = sa;
    a_dst[row * 8 + w] = sd;
    float* xo = x + (size_t)row * 128 + cb;
#pragma unroll
    for (int i = 0; i < 4; ++i)
      *(float4*)(xo + i * 4) =
          make_float4(acc[i * 4], acc[i * 4 + 1], acc[i * 4 + 2], acc[i * 4 + 3]);
  }
}

// ---------------- K3: histogram of dst ----------------
__global__ __launch_bounds__(256) void k_hist(const int* __restrict__ dst,
                                              int* __restrict__ counts) {
  int e = blockIdx.x * 256 + threadIdx.x;
  if (e < EE) atomicAdd(&counts[dst[e]], 1);
}

// ---------------- K4: per-block sums ----------------
__global__ __launch_bounds__(256) void k_blocksum(const int* __restrict__ counts,
                                                  int* __restrict__ partials, int n) {
  __shared__ int sm[256];
  int t = threadIdx.x;
  int gid = blockIdx.x * 256 + t;
  sm[t] = gid < n ? counts[gid] : 0;
  __syncthreads();
  for (int s = 128; s > 0; s >>= 1) {
    if (t < s) sm[t] += sm[t + s];
    __syncthreads();
  }
  if (t == 0) partials[blockIdx.x] = sm[0];
}

// ---------------- K5: exclusive scan of partials (single block) ----------------
__global__ __launch_bounds__(512) void k_scanpartials(int* __restrict__ partials, int nb) {
  __shared__ int sm[512];
  int t = threadIdx.x;
  int v = t < nb ? partials[t] : 0;
  sm[t] = v;
  __syncthreads();
  for (int off = 1; off < 512; off <<= 1) {
    int u = (t >= off) ? sm[t - off] : 0;
    __syncthreads();
    sm[t] += u;
    __syncthreads();
  }
  if (t < nb) partials[t] = sm[t] - v;  // exclusive
}

// ---------------- K6: final exclusive scan -> offsets, cursor ----------------
__global__ __launch_bounds__(256) void k_scanfinal(const int* __restrict__ counts,
                                                   const int* __restrict__ partials,
                                                   int* __restrict__ offsets,
                                                   int* __restrict__ cursor, int n) {
  __shared__ int sm[256];
  int t = threadIdx.x;
  int gid = blockIdx.x * 256 + t;
  int v = gid < n ? counts[gid] : 0;
  sm[t] = v;
  __syncthreads();
  for (int off = 1; off < 256; off <<= 1) {
    int u = (t >= off) ? sm[t - off] : 0;
    __syncthreads();
    sm[t] += u;
    __syncthreads();
  }
  int excl = partials[blockIdx.x] + sm[t] - v;
  if (gid < n) {
    offsets[gid] = excl;
    cursor[gid] = excl;
  }
  if (gid == n - 1) offsets[n] = excl + v;  // == EE
}

// ---------------- K7: fused a_edge + alpha + CSR scatter ----------------
__global__ __launch_bounds__(256) void k_scatter(
    const float* __restrict__ EA, const float* __restrict__ Wedge,
    const float* __restrict__ attE, const int* __restrict__ src,
    const int* __restrict__ dst, const float* __restrict__ a_src,
    const float* __restrict__ a_dst, int* __restrict__ cursor,
    int* __restrict__ sorted_src, int* __restrict__ sorted_orig,
    float* __restrict__ alpha) {
  __shared__ float M[16][8];  // M[d][h] = sum_c Wedge[d,h*16+c]*attE[h,c]
  int t = threadIdx.x;
  if (t < 128) {
    int d = t >> 3, h = t & 7;
    float s = 0.f;
#pragma unroll
    for (int c = 0; c < 16; ++c)
      s = fmaf(Wedge[d * 128 + h * 16 + c], attE[h * 16 + c], s);
    M[d][h] = s;
  }
  __syncthreads();
  int e = blockIdx.x * 256 + t;
  if (e >= EE) return;
  float ea[16];
  const float4* ea4 = (const float4*)(EA + (size_t)e * 16);
#pragma unroll
  for (int i = 0; i < 4; ++i) {
    float4 v = ea4[i];
    ea[i * 4] = v.x; ea[i * 4 + 1] = v.y; ea[i * 4 + 2] = v.z; ea[i * 4 + 3] = v.w;
  }
  int sv = src[e], dv = dst[e];
  const float4* as4 = (const float4*)(a_src + (size_t)sv * 8);
  const float4* ad4 = (const float4*)(a_dst + (size_t)dv * 8);
  float4 as0 = as4[0], as1 = as4[1];
  float4 ad0 = ad4[0], ad1 = ad4[1];
  float asv[8] = {as0.x, as0.y, as0.z, as0.w, as1.x, as1.y, as1.z, as1.w};
  float adv[8] = {ad0.x, ad0.y, ad0.z, ad0.w, ad1.x, ad1.y, ad1.z, ad1.w};
  float al[8];
#pragma unroll
  for (int h = 0; h < 8; ++h) {
    float s = 0.f;
#pragma unroll
    for (int d = 0; d < 16; ++d) s = fmaf(ea[d], M[d][h], s);
    float v = asv[h] + adv[h] + s;
    al[h] = v >= 0.f ? v : 0.2f * v;  // leaky_relu 0.2
  }
  int pos = atomicAdd(&cursor[dv], 1);
  sorted_src[pos] = sv;
  sorted_orig[pos] = e;
  float4* out4 = (float4*)(alpha + (size_t)pos * 8);
  out4[0] = make_float4(al[0], al[1], al[2], al[3]);
  out4[1] = make_float4(al[4], al[5], al[6], al[7]);
}

// ---------------- K8: segment softmax in-place (thread per (n,h)) ----------------
__global__ __launch_bounds__(256) void k_softmax(const int* __restrict__ offsets,
                                                 float* __restrict__ alpha) {
  int gid = blockIdx.x * 256 + threadIdx.x;
  if (gid >= NN * 8) return;
  int n = gid >> 3, h = gid & 7;
  int s = offsets[n], e = offsets[n + 1];
  float mx = -INFINITY;
  for (int i = s; i < e; ++i) mx = fmaxf(mx, alpha[(size_t)i * 8 + h]);
  float den = 0.f;
  for (int i = s; i < e; ++i) den += __expf(alpha[(size_t)i * 8 + h] - mx);
  float inv = 1.f / (den + 1e-16f);
  for (int i = s; i < e; ++i) {
    float v = __expf(alpha[(size_t)i * 8 + h] - mx);
    alpha[(size_t)i * 8 + h] = v * inv;
  }
}

// ---------------- K9: edge LN + linear + relu, scatter to original order ----------------
__global__ __launch_bounds__(256) void k_edgeout(
    const float* __restrict__ alpha, const int* __restrict__ sorted_orig,
    const float* __restrict__ g, const float* __restrict__ b,
    const float* __restrict__ ew, const float* __restrict__ eb,
    float* __restrict__ edge_out) {
  int i = blockIdx.x * 256 + threadIdx.x;
  if (i >= EE) return;
  const float4* a4 = (const float4*)(alpha + (size_t)i * 8);
  float4 v0 = a4[0], v1 = a4[1];
  float v[8] = {v0.x, v0.y, v0.z, v0.w, v1.x, v1.y, v1.z, v1.w};
  float mu = 0.f;
#pragma unroll
  for (int h = 0; h < 8; ++h) mu += v[h];
  mu *= 0.125f;
  float var = 0.f;
#pragma unroll
  for (int h = 0; h < 8; ++h) { float d = v[h] - mu; var += d * d; }
  var *= 0.125f;
  float r = rsqrtf(var + LN_EPS);
  float o = eb[0];
#pragma unroll
  for (int h = 0; h < 8; ++h)
    o += ((v[h] - mu) * r * g[h] + b[h]) * ew[h];
  edge_out[sorted_orig[i]] = fmaxf(o, 0.f);
}

// ---------------- K10: per-node aggregation + bias + LN + leaky ----------------
// 1 wave per node; lane l owns cols (2l, 2l+1).
__global__ __launch_bounds__(256) void k_aggregate(
    const int* __restrict__ offsets, const int* __restrict__ sorted_src,
    const float* __restrict__ alpha, const float* __restrict__ x,
    const float* __restrict__ bias, const float* __restrict__ g,
    const float* __restrict__ b, float* __restrict__ node_out) {
  int w = threadIdx.x >> 6, l = threadIdx.x & 63;
  int n = blockIdx.x * 4 + w;
  if (n >= NN) return;
  int s = offsets[n], e = offsets[n + 1];
  int h = l >> 3;
  float ax = 0.f, ay = 0.f;
  for (int i = s; i < e; ++i) {
    int sn = sorted_src[i];
    float a = alpha[(size_t)i * 8 + h];
    float2 xv = *(const float2*)(x + (size_t)sn * 128 + l * 2);
    ax = fmaf(a, xv.x, ax);
    ay = fmaf(a, xv.y, ay);
  }
  int c0 = l * 2;
  ax += bias[c0];
  ay += bias[c0 + 1];
  float sum = ax + ay;
#pragma unroll
  for (int off = 1; off < 64; off <<= 1) sum += __shfl_xor(sum, off);
  float mu = sum * (1.f / 128.f);
  float dx = ax - mu, dy = ay - mu;
  float ss = dx * dx + dy * dy;
#pragma unroll
  for (int off = 1; off < 64; off <<= 1) ss += __shfl_xor(ss, off);
  float r = rsqrtf(ss * (1.f / 128.f) + LN_EPS);
  float y0 = dx * r * g[c0] + b[c0];
  float y1 = dy * r * g[c0 + 1] + b[c0 + 1];
  y0 = y0 >= 0.f ? y0 : 0.01f * y0;
  y1 = y1 >= 0.f ? y1 : 0.01f * y1;
  *(float2*)(node_out + (size_t)n * 128 + c0) = make_float2(y0, y1);
}

extern "C" void kernel_launch(void* const* d_in, const int* in_sizes, int n_in,
                              void* d_out, int out_size, void* d_ws, size_t ws_size,
                              hipStream_t stream) {
  const void* edge_index = d_in[0];
  const float* point_attr = (const float*)d_in[1];
  const float* edge_attr = (const float*)d_in[2];
  const float* W = (const float*)d_in[3];
  const float* att_src = (const float*)d_in[4];
  const float* att_dst = (const float*)d_in[5];
  const float* W_edge = (const float*)d_in[6];
  const float* att_edge = (const float*)d_in[7];
  const float* bias = (const float*)d_in[8];
  const float* ln_node_g = (const float*)d_in[9];
  const float* ln_node_b = (const float*)d_in[10];
  const float* ln_edge_g = (const float*)d_in[11];
  const float* ln_edge_b = (const float*)d_in[12];
  const float* edge_w = (const float*)d_in[13];
  const float* edge_b = (const float*)d_in[14];

  char* wsb = (char*)d_ws;
  size_t o = 0;
  auto take = [&](size_t bytes) -> void* {
    void* p = wsb + o;
    o += (bytes + 255) & ~(size_t)255;
    return p;
  };
  int* flag = (int*)take(4);
  int* idx32 = (int*)take((size_t)2 * EE * 4);
  float* x = (float*)take((size_t)NN * 128 * 4);
  float* a_src = (float*)take((size_t)NN * 8 * 4);
  float* a_dst = (float*)take((size_t)NN * 8 * 4);
  int* counts = (int*)take((size_t)NN * 4);
  int* offsets = (int*)take((size_t)(NN + 1) * 4);
  int* cursor = (int*)take((size_t)NN * 4);
  int* partials = (int*)take(512 * 4);
  int* sorted_src = (int*)take((size_t)EE * 4);
  int* sorted_orig = (int*)take((size_t)EE * 4);
  float* alpha = (float*)take((size_t)EE * 8 * 4);

  const int* srcp = idx32;
  const int* dstp = idx32 + EE;
  float* node_out = (float*)d_out;
  float* edge_out = node_out + (size_t)NN * 128;

  int nb_scan = (NN + 255) / 256;  // 391

  hipMemsetAsync(counts, 0, (size_t)NN * 4, stream);

  k_detect<<<1, 64, 0, stream>>>(edge_index, flag);
  k_convert<<<(2 * EE + 255) / 256, 256, 0, stream>>>(edge_index, flag, idx32);
  k_gemm_node<<<(NN + 63) / 64, 512, 0, stream>>>(point_attr, W, att_src, att_dst,
                                                  x, a_src, a_dst, NN);
  k_hist<<<(EE + 255) / 256, 256, 0, stream>>>(dstp, counts);
  k_blocksum<<<nb_scan, 256, 0, stream>>>(counts, partials, NN);
  k_scanpartials<<<1, 512, 0, stream>>>(partials, nb_scan);
  k_scanfinal<<<nb_scan, 256, 0, stream>>>(counts, partials, offsets, cursor, NN);
  k_scatter<<<(EE + 255) / 256, 256, 0, stream>>>(edge_attr, W_edge, att_edge, srcp,
                                                  dstp, a_src, a_dst, cursor,
                                                  sorted_src, sorted_orig, alpha);
  k_softmax<<<(NN * 8 + 255) / 256, 256, 0, stream>>>(offsets, alpha);
  k_edgeout<<<(EE + 255) / 256, 256, 0, stream>>>(alpha, sorted_orig, ln_edge_g,
                                                  ln_edge_b, edge_w, edge_b, edge_out);
  k_aggregate<<<(NN + 3) / 4, 256, 0, stream>>>(offsets, sorted_src, alpha, x, bias,
                                                ln_node_g, ln_node_b, node_out);
}

// Round 2
// 475.769 us; speedup vs baseline: 1.2046x; 1.2046x over previous
//
#include <hip/hip_runtime.h>
#include <hip/hip_bf16.h>

#define NN 100000
#define EE 1600000
#define LN_EPS 1e-5f

__device__ __forceinline__ float bf_lo(unsigned u) {
  union { unsigned i; float f; } c; c.i = u << 16; return c.f;
}
__device__ __forceinline__ float bf_hi(unsigned u) {
  union { unsigned i; float f; } c; c.i = u & 0xffff0000u; return c.f;
}
__device__ __forceinline__ unsigned short f2bf(float f) {
  union { float f; unsigned i; } c; c.f = f;
  unsigned b = c.i + 0x7fffu + ((c.i >> 16) & 1u);
  return (unsigned short)(b >> 16);
}

// ---------------- K0: detect int64 vs int32 edge_index ----------------
__global__ void k_detect(const void* __restrict__ ei, int* __restrict__ flag) {
  if (threadIdx.x == 0 && blockIdx.x == 0) {
    const unsigned long long* p = (const unsigned long long*)ei;
    int ok = 1;
    for (int i = 0; i < 256; ++i)
      if (p[i] >= (unsigned long long)NN) { ok = 0; break; }
    *flag = ok;  // 1 => int64, 0 => int32
  }
}

// ---------------- K1: normalize edge_index to int32 + dst histogram ----------------
__global__ __launch_bounds__(256) void k_convert_hist(const void* __restrict__ ei,
                                                      const int* __restrict__ flag,
                                                      int* __restrict__ idx32,
                                                      int* __restrict__ counts) {
  int i = blockIdx.x * 256 + threadIdx.x;
  if (i >= 2 * EE) return;
  int v;
  if (*flag) v = (int)((const long long*)ei)[i];
  else       v = ((const int*)ei)[i];
  idx32[i] = v;
  if (i >= EE) atomicAdd(&counts[v], 1);
}

// ---------------- K2: x = P@W (bf16 out), a_src, a_dst ----------------
__global__ __launch_bounds__(512) void k_gemm_node(
    const float* __restrict__ P, const float* __restrict__ W,
    const float* __restrict__ attS, const float* __restrict__ attD,
    unsigned* __restrict__ xb, float* __restrict__ a_src, float* __restrict__ a_dst,
    int nrows) {
  __shared__ float Rl[32 * 66];
  int t = threadIdx.x;
  int w = __builtin_amdgcn_readfirstlane(t >> 6);
  int l = t & 63;
  int rb = blockIdx.x * 64;
  int cb = w * 16;
  float acc[16];
#pragma unroll
  for (int j = 0; j < 16; ++j) acc[j] = 0.f;

  for (int kc = 0; kc < 4; ++kc) {
    __syncthreads();
    {
      int row = t >> 3;
      int k0 = (t & 7) * 4;
      int grow = rb + row;
      float4 v = make_float4(0.f, 0.f, 0.f, 0.f);
      if (grow < nrows)
        v = *(const float4*)(P + (size_t)grow * 128 + kc * 32 + k0);
      Rl[(k0 + 0) * 66 + row] = v.x;
      Rl[(k0 + 1) * 66 + row] = v.y;
      Rl[(k0 + 2) * 66 + row] = v.z;
      Rl[(k0 + 3) * 66 + row] = v.w;
    }
    __syncthreads();
    const float* Wp = W + (size_t)(kc * 32) * 128 + cb;
#pragma unroll 8
    for (int k = 0; k < 32; ++k) {
      float rv = Rl[k * 66 + l];
#pragma unroll
      for (int j = 0; j < 16; ++j) acc[j] = fmaf(rv, Wp[k * 128 + j], acc[j]);
    }
  }
  int row = rb + l;
  if (row < nrows) {
    float sa = 0.f, sd = 0.f;
#pragma unroll
    for (int j = 0; j < 16; ++j) {
      sa = fmaf(acc[j], attS[cb + j], sa);
      sd = fmaf(acc[j], attD[cb + j], sd);
    }
    a_src[row * 8 + w] = sa;
    a_dst[row * 8 + w] = sd;
    unsigned pk[8];
#pragma unroll
    for (int m = 0; m < 8; ++m)
      pk[m] = (unsigned)f2bf(acc[2 * m]) | ((unsigned)f2bf(acc[2 * m + 1]) << 16);
    unsigned* xo = xb + (size_t)row * 64 + cb / 2;
    *(uint4*)(xo) = make_uint4(pk[0], pk[1], pk[2], pk[3]);
    *(uint4*)(xo + 4) = make_uint4(pk[4], pk[5], pk[6], pk[7]);
  }
}

// ---------------- K4: per-block sums ----------------
__global__ __launch_bounds__(256) void k_blocksum(const int* __restrict__ counts,
                                                  int* __restrict__ partials, int n) {
  __shared__ int sm[256];
  int t = threadIdx.x;
  int gid = blockIdx.x * 256 + t;
  sm[t] = gid < n ? counts[gid] : 0;
  __syncthreads();
  for (int s = 128; s > 0; s >>= 1) {
    if (t < s) sm[t] += sm[t + s];
    __syncthreads();
  }
  if (t == 0) partials[blockIdx.x] = sm[0];
}

// ---------------- K5: exclusive scan of partials ----------------
__global__ __launch_bounds__(512) void k_scanpartials(int* __restrict__ partials, int nb) {
  __shared__ int sm[512];
  int t = threadIdx.x;
  int v = t < nb ? partials[t] : 0;
  sm[t] = v;
  __syncthreads();
  for (int off = 1; off < 512; off <<= 1) {
    int u = (t >= off) ? sm[t - off] : 0;
    __syncthreads();
    sm[t] += u;
    __syncthreads();
  }
  if (t < nb) partials[t] = sm[t] - v;
}

// ---------------- K6: final exclusive scan -> offsets, cursor ----------------
__global__ __launch_bounds__(256) void k_scanfinal(const int* __restrict__ counts,
                                                   const int* __restrict__ partials,
                                                   int* __restrict__ offsets,
                                                   int* __restrict__ cursor, int n) {
  __shared__ int sm[256];
  int t = threadIdx.x;
  int gid = blockIdx.x * 256 + t;
  int v = gid < n ? counts[gid] : 0;
  sm[t] = v;
  __syncthreads();
  for (int off = 1; off < 256; off <<= 1) {
    int u = (t >= off) ? sm[t - off] : 0;
    __syncthreads();
    sm[t] += u;
    __syncthreads();
  }
  int excl = partials[blockIdx.x] + sm[t] - v;
  if (gid < n) {
    offsets[gid] = excl;
    cursor[gid] = excl;
  }
  if (gid == n - 1) offsets[n] = excl + v;
}

// ---------------- K7: alpha (sequential write) + CSR index scatter ----------------
__global__ __launch_bounds__(256) void k_scatter(
    const float* __restrict__ EA, const float* __restrict__ Wedge,
    const float* __restrict__ attE, const int* __restrict__ src,
    const int* __restrict__ dst, const float* __restrict__ a_src,
    const float* __restrict__ a_dst, int* __restrict__ cursor,
    int2* __restrict__ pair, float* __restrict__ alpha) {
  __shared__ float M[16][8];
  int t = threadIdx.x;
  if (t < 128) {
    int d = t >> 3, h = t & 7;
    float s = 0.f;
#pragma unroll
    for (int c = 0; c < 16; ++c)
      s = fmaf(Wedge[d * 128 + h * 16 + c], attE[h * 16 + c], s);
    M[d][h] = s;
  }
  __syncthreads();
  int e = blockIdx.x * 256 + t;
  if (e >= EE) return;
  float ea[16];
  const float4* ea4 = (const float4*)(EA + (size_t)e * 16);
#pragma unroll
  for (int i = 0; i < 4; ++i) {
    float4 v = ea4[i];
    ea[i * 4] = v.x; ea[i * 4 + 1] = v.y; ea[i * 4 + 2] = v.z; ea[i * 4 + 3] = v.w;
  }
  int sv = src[e], dv = dst[e];
  const float4* as4 = (const float4*)(a_src + (size_t)sv * 8);
  const float4* ad4 = (const float4*)(a_dst + (size_t)dv * 8);
  float4 as0 = as4[0], as1 = as4[1];
  float4 ad0 = ad4[0], ad1 = ad4[1];
  float asv[8] = {as0.x, as0.y, as0.z, as0.w, as1.x, as1.y, as1.z, as1.w};
  float adv[8] = {ad0.x, ad0.y, ad0.z, ad0.w, ad1.x, ad1.y, ad1.z, ad1.w};
  float al[8];
#pragma unroll
  for (int h = 0; h < 8; ++h) {
    float s = 0.f;
#pragma unroll
    for (int d = 0; d < 16; ++d) s = fmaf(ea[d], M[d][h], s);
    float v = asv[h] + adv[h] + s;
    al[h] = v >= 0.f ? v : 0.2f * v;
  }
  // sequential, fully coalesced alpha write (original edge order)
  float4* out4 = (float4*)(alpha + (size_t)e * 8);
  out4[0] = make_float4(al[0], al[1], al[2], al[3]);
  out4[1] = make_float4(al[4], al[5], al[6], al[7]);
  int pos = atomicAdd(&cursor[dv], 1);
  pair[pos] = make_int2(e, sv);  // 8 B random write (was 40 B)
}

// ---------------- K8: fused softmax + aggregation + bias + LN + leaky ----------------
// one wave per node; lane l owns cols (2l,2l+1), head h = l>>3.
__global__ __launch_bounds__(512) void k_megaagg(
    const int* __restrict__ offsets, const int2* __restrict__ pair,
    const float* __restrict__ alpha, const unsigned* __restrict__ xb,
    const float* __restrict__ bias, const float* __restrict__ g,
    const float* __restrict__ b, float* __restrict__ node_out,
    float* __restrict__ minv) {
  int w = threadIdx.x >> 6, l = threadIdx.x & 63;
  int n = blockIdx.x * 8 + w;
  if (n >= NN) return;
  int s = offsets[n], e = offsets[n + 1];
  int h = l >> 3;
  // pass 1: per-head max (unroll 4)
  float mx = -INFINITY;
  int i = s;
  for (; i + 3 < e; i += 4) {
    int2 p0 = pair[i], p1 = pair[i + 1], p2 = pair[i + 2], p3 = pair[i + 3];
    float a0 = alpha[(size_t)p0.x * 8 + h];
    float a1 = alpha[(size_t)p1.x * 8 + h];
    float a2 = alpha[(size_t)p2.x * 8 + h];
    float a3 = alpha[(size_t)p3.x * 8 + h];
    mx = fmaxf(mx, fmaxf(fmaxf(a0, a1), fmaxf(a2, a3)));
  }
  for (; i < e; ++i) mx = fmaxf(mx, alpha[(size_t)pair[i].x * 8 + h]);
  // pass 2: den + weighted accumulation (unroll 2, independent chains)
  float den0 = 0.f, den1 = 0.f, axA = 0.f, ayA = 0.f, axB = 0.f, ayB = 0.f;
  for (i = s; i + 1 < e; i += 2) {
    int2 p0 = pair[i], p1 = pair[i + 1];
    float a0 = alpha[(size_t)p0.x * 8 + h];
    float a1 = alpha[(size_t)p1.x * 8 + h];
    unsigned x0 = xb[(size_t)p0.y * 64 + l];
    unsigned x1 = xb[(size_t)p1.y * 64 + l];
    float e0 = __expf(a0 - mx), e1 = __expf(a1 - mx);
    den0 += e0; den1 += e1;
    axA = fmaf(e0, bf_lo(x0), axA); ayA = fmaf(e0, bf_hi(x0), ayA);
    axB = fmaf(e1, bf_lo(x1), axB); ayB = fmaf(e1, bf_hi(x1), ayB);
  }
  if (i < e) {
    int2 p0 = pair[i];
    float a0 = alpha[(size_t)p0.x * 8 + h];
    unsigned x0 = xb[(size_t)p0.y * 64 + l];
    float e0 = __expf(a0 - mx);
    den0 += e0;
    axA = fmaf(e0, bf_lo(x0), axA); ayA = fmaf(e0, bf_hi(x0), ayA);
  }
  float den = den0 + den1;
  float inv = 1.f / (den + 1e-16f);
  if ((l & 7) == 0) {
    minv[(size_t)n * 16 + h] = mx;
    minv[(size_t)n * 16 + 8 + h] = inv;
  }
  int c0 = l * 2;
  float ax = (axA + axB) * inv + bias[c0];
  float ay = (ayA + ayB) * inv + bias[c0 + 1];
  float sum = ax + ay;
#pragma unroll
  for (int off = 1; off < 64; off <<= 1) sum += __shfl_xor(sum, off);
  float mu = sum * (1.f / 128.f);
  float dx = ax - mu, dy = ay - mu;
  float ss = dx * dx + dy * dy;
#pragma unroll
  for (int off = 1; off < 64; off <<= 1) ss += __shfl_xor(ss, off);
  float r = rsqrtf(ss * (1.f / 128.f) + LN_EPS);
  float y0 = dx * r * g[c0] + b[c0];
  float y1 = dy * r * g[c0 + 1] + b[c0 + 1];
  y0 = y0 >= 0.f ? y0 : 0.01f * y0;
  y1 = y1 >= 0.f ? y1 : 0.01f * y1;
  *(float2*)(node_out + (size_t)n * 128 + c0) = make_float2(y0, y1);
}

// ---------------- K9: edge LN + linear + relu, original order (all sequential) ---
__global__ __launch_bounds__(256) void k_edgeout(
    const float* __restrict__ alpha, const int* __restrict__ dst,
    const float* __restrict__ minv, const float* __restrict__ g,
    const float* __restrict__ b, const float* __restrict__ ew,
    const float* __restrict__ eb, float* __restrict__ edge_out) {
  int i = blockIdx.x * 256 + threadIdx.x;
  if (i >= EE) return;
  int dv = dst[i];
  const float* mi = minv + (size_t)dv * 16;
  float4 m0 = *(const float4*)(mi);
  float4 m1 = *(const float4*)(mi + 4);
  float4 i0 = *(const float4*)(mi + 8);
  float4 i1 = *(const float4*)(mi + 12);
  float mm[8] = {m0.x, m0.y, m0.z, m0.w, m1.x, m1.y, m1.z, m1.w};
  float iv[8] = {i0.x, i0.y, i0.z, i0.w, i1.x, i1.y, i1.z, i1.w};
  const float4* a4 = (const float4*)(alpha + (size_t)i * 8);
  float4 v0 = a4[0], v1 = a4[1];
  float v[8] = {v0.x, v0.y, v0.z, v0.w, v1.x, v1.y, v1.z, v1.w};
  float p[8];
#pragma unroll
  for (int h = 0; h < 8; ++h) p[h] = __expf(v[h] - mm[h]) * iv[h];
  float mu = 0.f;
#pragma unroll
  for (int h = 0; h < 8; ++h) mu += p[h];
  mu *= 0.125f;
  float var = 0.f;
#pragma unroll
  for (int h = 0; h < 8; ++h) { float d = p[h] - mu; var += d * d; }
  var *= 0.125f;
  float r = rsqrtf(var + LN_EPS);
  float o = eb[0];
#pragma unroll
  for (int h = 0; h < 8; ++h)
    o += ((p[h] - mu) * r * g[h] + b[h]) * ew[h];
  edge_out[i] = fmaxf(o, 0.f);
}

extern "C" void kernel_launch(void* const* d_in, const int* in_sizes, int n_in,
                              void* d_out, int out_size, void* d_ws, size_t ws_size,
                              hipStream_t stream) {
  const void* edge_index = d_in[0];
  const float* point_attr = (const float*)d_in[1];
  const float* edge_attr = (const float*)d_in[2];
  const float* W = (const float*)d_in[3];
  const float* att_src = (const float*)d_in[4];
  const float* att_dst = (const float*)d_in[5];
  const float* W_edge = (const float*)d_in[6];
  const float* att_edge = (const float*)d_in[7];
  const float* bias = (const float*)d_in[8];
  const float* ln_node_g = (const float*)d_in[9];
  const float* ln_node_b = (const float*)d_in[10];
  const float* ln_edge_g = (const float*)d_in[11];
  const float* ln_edge_b = (const float*)d_in[12];
  const float* edge_w = (const float*)d_in[13];
  const float* edge_b = (const float*)d_in[14];

  char* wsb = (char*)d_ws;
  size_t o = 0;
  auto take = [&](size_t bytes) -> void* {
    void* p = wsb + o;
    o += (bytes + 255) & ~(size_t)255;
    return p;
  };
  int* flag = (int*)take(4);
  int* idx32 = (int*)take((size_t)2 * EE * 4);
  unsigned* xb = (unsigned*)take((size_t)NN * 128 * 2);
  float* a_src = (float*)take((size_t)NN * 8 * 4);
  float* a_dst = (float*)take((size_t)NN * 8 * 4);
  int* counts = (int*)take((size_t)NN * 4);
  int* offsets = (int*)take((size_t)(NN + 1) * 4);
  int* cursor = (int*)take((size_t)NN * 4);
  int* partials = (int*)take(512 * 4);
  int2* pair = (int2*)take((size_t)EE * 8);
  float* alpha = (float*)take((size_t)EE * 8 * 4);
  float* minv = (float*)take((size_t)NN * 16 * 4);

  const int* srcp = idx32;
  const int* dstp = idx32 + EE;
  float* node_out = (float*)d_out;
  float* edge_out = node_out + (size_t)NN * 128;

  int nb_scan = (NN + 255) / 256;  // 391

  hipMemsetAsync(counts, 0, (size_t)NN * 4, stream);

  k_detect<<<1, 64, 0, stream>>>(edge_index, flag);
  k_convert_hist<<<(2 * EE + 255) / 256, 256, 0, stream>>>(edge_index, flag, idx32, counts);
  k_gemm_node<<<(NN + 63) / 64, 512, 0, stream>>>(point_attr, W, att_src, att_dst,
                                                  xb, a_src, a_dst, NN);
  k_blocksum<<<nb_scan, 256, 0, stream>>>(counts, partials, NN);
  k_scanpartials<<<1, 512, 0, stream>>>(partials, nb_scan);
  k_scanfinal<<<nb_scan, 256, 0, stream>>>(counts, partials, offsets, cursor, NN);
  k_scatter<<<(EE + 255) / 256, 256, 0, stream>>>(edge_attr, W_edge, att_edge, srcp,
                                                  dstp, a_src, a_dst, cursor,
                                                  pair, alpha);
  k_megaagg<<<(NN + 7) / 8, 512, 0, stream>>>(offsets, pair, alpha, xb, bias,
                                              ln_node_g, ln_node_b, node_out, minv);
  k_edgeout<<<(EE + 255) / 256, 256, 0, stream>>>(alpha, dstp, minv, ln_edge_g,
                                                  ln_edge_b, edge_w, edge_b, edge_out);
}

// Round 3
// 384.241 us; speedup vs baseline: 1.4916x; 1.2382x over previous
//
#include <hip/hip_runtime.h>
#include <hip/hip_bf16.h>

#define NN 100000
#define EE 1600000
#define LN_EPS 1e-5f

__device__ __forceinline__ float bf_lo(unsigned u) {
  union { unsigned i; float f; } c; c.i = u << 16; return c.f;
}
__device__ __forceinline__ float bf_hi(unsigned u) {
  union { unsigned i; float f; } c; c.i = u & 0xffff0000u; return c.f;
}
__device__ __forceinline__ unsigned short f2bf(float f) {
  union { float f; unsigned i; } c; c.f = f;
  unsigned b = c.i + 0x7fffu + ((c.i >> 16) & 1u);
  return (unsigned short)(b >> 16);
}

// ---------------- K0: detect int64 vs int32 edge_index ----------------
__global__ void k_detect(const void* __restrict__ ei, int* __restrict__ flag) {
  if (threadIdx.x == 0 && blockIdx.x == 0) {
    const unsigned long long* p = (const unsigned long long*)ei;
    int ok = 1;
    for (int i = 0; i < 256; ++i)
      if (p[i] >= (unsigned long long)NN) { ok = 0; break; }
    *flag = ok;  // 1 => int64, 0 => int32
  }
}

// ---------------- K1: normalize edge_index to int32 + dst histogram ----------------
__global__ __launch_bounds__(256) void k_convert_hist(const void* __restrict__ ei,
                                                      const int* __restrict__ flag,
                                                      int* __restrict__ idx32,
                                                      int* __restrict__ counts) {
  int i = blockIdx.x * 256 + threadIdx.x;
  if (i >= 2 * EE) return;
  int v;
  if (*flag) v = (int)((const long long*)ei)[i];
  else       v = ((const int*)ei)[i];
  idx32[i] = v;
  if (i >= EE) atomicAdd(&counts[v], 1);
}

// ---------------- K2: x = P@W (bf16 out), a_src, a_dst ----------------
__global__ __launch_bounds__(512) void k_gemm_node(
    const float* __restrict__ P, const float* __restrict__ W,
    const float* __restrict__ attS, const float* __restrict__ attD,
    unsigned* __restrict__ xb, float* __restrict__ a_src, float* __restrict__ a_dst,
    int nrows) {
  __shared__ float Rl[32 * 66];
  int t = threadIdx.x;
  int w = __builtin_amdgcn_readfirstlane(t >> 6);
  int l = t & 63;
  int rb = blockIdx.x * 64;
  int cb = w * 16;
  float acc[16];
#pragma unroll
  for (int j = 0; j < 16; ++j) acc[j] = 0.f;

  for (int kc = 0; kc < 4; ++kc) {
    __syncthreads();
    {
      int row = t >> 3;
      int k0 = (t & 7) * 4;
      int grow = rb + row;
      float4 v = make_float4(0.f, 0.f, 0.f, 0.f);
      if (grow < nrows)
        v = *(const float4*)(P + (size_t)grow * 128 + kc * 32 + k0);
      Rl[(k0 + 0) * 66 + row] = v.x;
      Rl[(k0 + 1) * 66 + row] = v.y;
      Rl[(k0 + 2) * 66 + row] = v.z;
      Rl[(k0 + 3) * 66 + row] = v.w;
    }
    __syncthreads();
    const float* Wp = W + (size_t)(kc * 32) * 128 + cb;
#pragma unroll 8
    for (int k = 0; k < 32; ++k) {
      float rv = Rl[k * 66 + l];
#pragma unroll
      for (int j = 0; j < 16; ++j) acc[j] = fmaf(rv, Wp[k * 128 + j], acc[j]);
    }
  }
  int row = rb + l;
  if (row < nrows) {
    float sa = 0.f, sd = 0.f;
#pragma unroll
    for (int j = 0; j < 16; ++j) {
      sa = fmaf(acc[j], attS[cb + j], sa);
      sd = fmaf(acc[j], attD[cb + j], sd);
    }
    a_src[row * 8 + w] = sa;
    a_dst[row * 8 + w] = sd;
    unsigned pk[8];
#pragma unroll
    for (int m = 0; m < 8; ++m)
      pk[m] = (unsigned)f2bf(acc[2 * m]) | ((unsigned)f2bf(acc[2 * m + 1]) << 16);
    unsigned* xo = xb + (size_t)row * 64 + cb / 2;
    *(uint4*)(xo) = make_uint4(pk[0], pk[1], pk[2], pk[3]);
    *(uint4*)(xo + 4) = make_uint4(pk[4], pk[5], pk[6], pk[7]);
  }
}

// ---------------- K4: per-block sums ----------------
__global__ __launch_bounds__(256) void k_blocksum(const int* __restrict__ counts,
                                                  int* __restrict__ partials, int n) {
  __shared__ int sm[256];
  int t = threadIdx.x;
  int gid = blockIdx.x * 256 + t;
  sm[t] = gid < n ? counts[gid] : 0;
  __syncthreads();
  for (int s = 128; s > 0; s >>= 1) {
    if (t < s) sm[t] += sm[t + s];
    __syncthreads();
  }
  if (t == 0) partials[blockIdx.x] = sm[0];
}

// ---------------- K5: exclusive scan of partials ----------------
__global__ __launch_bounds__(512) void k_scanpartials(int* __restrict__ partials, int nb) {
  __shared__ int sm[512];
  int t = threadIdx.x;
  int v = t < nb ? partials[t] : 0;
  sm[t] = v;
  __syncthreads();
  for (int off = 1; off < 512; off <<= 1) {
    int u = (t >= off) ? sm[t - off] : 0;
    __syncthreads();
    sm[t] += u;
    __syncthreads();
  }
  if (t < nb) partials[t] = sm[t] - v;
}

// ---------------- K6: final exclusive scan -> offsets, cursor ----------------
__global__ __launch_bounds__(256) void k_scanfinal(const int* __restrict__ counts,
                                                   const int* __restrict__ partials,
                                                   int* __restrict__ offsets,
                                                   int* __restrict__ cursor, int n) {
  __shared__ int sm[256];
  int t = threadIdx.x;
  int gid = blockIdx.x * 256 + t;
  int v = gid < n ? counts[gid] : 0;
  sm[t] = v;
  __syncthreads();
  for (int off = 1; off < 256; off <<= 1) {
    int u = (t >= off) ? sm[t - off] : 0;
    __syncthreads();
    sm[t] += u;
    __syncthreads();
  }
  int excl = partials[blockIdx.x] + sm[t] - v;
  if (gid < n) {
    offsets[gid] = excl;
    cursor[gid] = excl;
  }
  if (gid == n - 1) offsets[n] = excl + v;
}

// ---------------- K7: alpha (sequential write) + CSR index scatter ----------------
__global__ __launch_bounds__(256) void k_scatter(
    const float* __restrict__ EA, const float* __restrict__ Wedge,
    const float* __restrict__ attE, const int* __restrict__ src,
    const int* __restrict__ dst, const float* __restrict__ a_src,
    const float* __restrict__ a_dst, int* __restrict__ cursor,
    int2* __restrict__ pair, float* __restrict__ alpha) {
  __shared__ float M[16][8];
  int t = threadIdx.x;
  if (t < 128) {
    int d = t >> 3, h = t & 7;
    float s = 0.f;
#pragma unroll
    for (int c = 0; c < 16; ++c)
      s = fmaf(Wedge[d * 128 + h * 16 + c], attE[h * 16 + c], s);
    M[d][h] = s;
  }
  __syncthreads();
  int e = blockIdx.x * 256 + t;
  if (e >= EE) return;
  float ea[16];
  const float4* ea4 = (const float4*)(EA + (size_t)e * 16);
#pragma unroll
  for (int i = 0; i < 4; ++i) {
    float4 v = ea4[i];
    ea[i * 4] = v.x; ea[i * 4 + 1] = v.y; ea[i * 4 + 2] = v.z; ea[i * 4 + 3] = v.w;
  }
  int sv = src[e], dv = dst[e];
  const float4* as4 = (const float4*)(a_src + (size_t)sv * 8);
  const float4* ad4 = (const float4*)(a_dst + (size_t)dv * 8);
  float4 as0 = as4[0], as1 = as4[1];
  float4 ad0 = ad4[0], ad1 = ad4[1];
  float asv[8] = {as0.x, as0.y, as0.z, as0.w, as1.x, as1.y, as1.z, as1.w};
  float adv[8] = {ad0.x, ad0.y, ad0.z, ad0.w, ad1.x, ad1.y, ad1.z, ad1.w};
  float al[8];
#pragma unroll
  for (int h = 0; h < 8; ++h) {
    float s = 0.f;
#pragma unroll
    for (int d = 0; d < 16; ++d) s = fmaf(ea[d], M[d][h], s);
    float v = asv[h] + adv[h] + s;
    al[h] = v >= 0.f ? v : 0.2f * v;
  }
  float4* out4 = (float4*)(alpha + (size_t)e * 8);
  out4[0] = make_float4(al[0], al[1], al[2], al[3]);
  out4[1] = make_float4(al[4], al[5], al[6], al[7]);
  int pos = atomicAdd(&cursor[dv], 1);
  pair[pos] = make_int2(e, sv);
}

// ---------------- K8: fused softmax (no-max) + aggregation + bias + LN + leaky ----
// one wave per node; lane l owns cols (2l,2l+1), head h = l>>3.
// single pass: den = sum exp(a), acc = sum exp(a)*x ; division at the end.
__global__ __launch_bounds__(512) void k_megaagg(
    const int* __restrict__ offsets, const int2* __restrict__ pair,
    const float* __restrict__ alpha, const unsigned* __restrict__ xb,
    const float* __restrict__ bias, const float* __restrict__ g,
    const float* __restrict__ b, float* __restrict__ node_out,
    float* __restrict__ inv_arr) {
  int w = threadIdx.x >> 6, l = threadIdx.x & 63;
  int n = blockIdx.x * 8 + w;
  if (n >= NN) return;
  int s = offsets[n], e = offsets[n + 1];
  int h = l >> 3;
  float dn0 = 0.f, dn1 = 0.f, dn2 = 0.f, dn3 = 0.f;
  float ax0 = 0.f, ay0 = 0.f, ax1 = 0.f, ay1 = 0.f;
  float ax2 = 0.f, ay2 = 0.f, ax3 = 0.f, ay3 = 0.f;
  int i = s;
  for (; i + 3 < e; i += 4) {
    int2 p0 = pair[i], p1 = pair[i + 1], p2 = pair[i + 2], p3 = pair[i + 3];
    float a0 = alpha[(size_t)p0.x * 8 + h];
    float a1 = alpha[(size_t)p1.x * 8 + h];
    float a2 = alpha[(size_t)p2.x * 8 + h];
    float a3 = alpha[(size_t)p3.x * 8 + h];
    unsigned x0 = xb[(size_t)p0.y * 64 + l];
    unsigned x1 = xb[(size_t)p1.y * 64 + l];
    unsigned x2 = xb[(size_t)p2.y * 64 + l];
    unsigned x3 = xb[(size_t)p3.y * 64 + l];
    float e0 = __expf(a0), e1 = __expf(a1), e2 = __expf(a2), e3 = __expf(a3);
    dn0 += e0; dn1 += e1; dn2 += e2; dn3 += e3;
    ax0 = fmaf(e0, bf_lo(x0), ax0); ay0 = fmaf(e0, bf_hi(x0), ay0);
    ax1 = fmaf(e1, bf_lo(x1), ax1); ay1 = fmaf(e1, bf_hi(x1), ay1);
    ax2 = fmaf(e2, bf_lo(x2), ax2); ay2 = fmaf(e2, bf_hi(x2), ay2);
    ax3 = fmaf(e3, bf_lo(x3), ax3); ay3 = fmaf(e3, bf_hi(x3), ay3);
  }
  for (; i < e; ++i) {
    int2 p0 = pair[i];
    float a0 = alpha[(size_t)p0.x * 8 + h];
    unsigned x0 = xb[(size_t)p0.y * 64 + l];
    float e0 = __expf(a0);
    dn0 += e0;
    ax0 = fmaf(e0, bf_lo(x0), ax0); ay0 = fmaf(e0, bf_hi(x0), ay0);
  }
  float den = (dn0 + dn1) + (dn2 + dn3);
  float inv = 1.f / (den + 1e-16f);
  if ((l & 7) == 0) inv_arr[(size_t)n * 8 + h] = inv;
  int c0 = l * 2;
  float ax = ((ax0 + ax1) + (ax2 + ax3)) * inv + bias[c0];
  float ay = ((ay0 + ay1) + (ay2 + ay3)) * inv + bias[c0 + 1];
  float sum = ax + ay;
#pragma unroll
  for (int off = 1; off < 64; off <<= 1) sum += __shfl_xor(sum, off);
  float mu = sum * (1.f / 128.f);
  float dx = ax - mu, dy = ay - mu;
  float ss = dx * dx + dy * dy;
#pragma unroll
  for (int off = 1; off < 64; off <<= 1) ss += __shfl_xor(ss, off);
  float r = rsqrtf(ss * (1.f / 128.f) + LN_EPS);
  float y0 = dx * r * g[c0] + b[c0];
  float y1 = dy * r * g[c0 + 1] + b[c0 + 1];
  y0 = y0 >= 0.f ? y0 : 0.01f * y0;
  y1 = y1 >= 0.f ? y1 : 0.01f * y1;
  *(float2*)(node_out + (size_t)n * 128 + c0) = make_float2(y0, y1);
}

// ---------------- K9: edge LN + linear + relu, original order (all sequential) ---
__global__ __launch_bounds__(256) void k_edgeout(
    const float* __restrict__ alpha, const int* __restrict__ dst,
    const float* __restrict__ inv_arr, const float* __restrict__ g,
    const float* __restrict__ b, const float* __restrict__ ew,
    const float* __restrict__ eb, float* __restrict__ edge_out) {
  int i = blockIdx.x * 256 + threadIdx.x;
  if (i >= EE) return;
  int dv = dst[i];
  const float4* iv4 = (const float4*)(inv_arr + (size_t)dv * 8);
  float4 i0 = iv4[0], i1 = iv4[1];
  float iv[8] = {i0.x, i0.y, i0.z, i0.w, i1.x, i1.y, i1.z, i1.w};
  const float4* a4 = (const float4*)(alpha + (size_t)i * 8);
  float4 v0 = a4[0], v1 = a4[1];
  float v[8] = {v0.x, v0.y, v0.z, v0.w, v1.x, v1.y, v1.z, v1.w};
  float p[8];
#pragma unroll
  for (int h = 0; h < 8; ++h) p[h] = __expf(v[h]) * iv[h];
  float mu = 0.f;
#pragma unroll
  for (int h = 0; h < 8; ++h) mu += p[h];
  mu *= 0.125f;
  float var = 0.f;
#pragma unroll
  for (int h = 0; h < 8; ++h) { float d = p[h] - mu; var += d * d; }
  var *= 0.125f;
  float r = rsqrtf(var + LN_EPS);
  float o = eb[0];
#pragma unroll
  for (int h = 0; h < 8; ++h)
    o += ((p[h] - mu) * r * g[h] + b[h]) * ew[h];
  edge_out[i] = fmaxf(o, 0.f);
}

extern "C" void kernel_launch(void* const* d_in, const int* in_sizes, int n_in,
                              void* d_out, int out_size, void* d_ws, size_t ws_size,
                              hipStream_t stream) {
  const void* edge_index = d_in[0];
  const float* point_attr = (const float*)d_in[1];
  const float* edge_attr = (const float*)d_in[2];
  const float* W = (const float*)d_in[3];
  const float* att_src = (const float*)d_in[4];
  const float* att_dst = (const float*)d_in[5];
  const float* W_edge = (const float*)d_in[6];
  const float* att_edge = (const float*)d_in[7];
  const float* bias = (const float*)d_in[8];
  const float* ln_node_g = (const float*)d_in[9];
  const float* ln_node_b = (const float*)d_in[10];
  const float* ln_edge_g = (const float*)d_in[11];
  const float* ln_edge_b = (const float*)d_in[12];
  const float* edge_w = (const float*)d_in[13];
  const float* edge_b = (const float*)d_in[14];

  char* wsb = (char*)d_ws;
  size_t o = 0;
  auto take = [&](size_t bytes) -> void* {
    void* p = wsb + o;
    o += (bytes + 255) & ~(size_t)255;
    return p;
  };
  int* flag = (int*)take(4);
  int* idx32 = (int*)take((size_t)2 * EE * 4);
  unsigned* xb = (unsigned*)take((size_t)NN * 128 * 2);
  float* a_src = (float*)take((size_t)NN * 8 * 4);
  float* a_dst = (float*)take((size_t)NN * 8 * 4);
  int* counts = (int*)take((size_t)NN * 4);
  int* offsets = (int*)take((size_t)(NN + 1) * 4);
  int* cursor = (int*)take((size_t)NN * 4);
  int* partials = (int*)take(512 * 4);
  int2* pair = (int2*)take((size_t)EE * 8);
  float* alpha = (float*)take((size_t)EE * 8 * 4);
  float* inv_arr = (float*)take((size_t)NN * 8 * 4);

  const int* srcp = idx32;
  const int* dstp = idx32 + EE;
  float* node_out = (float*)d_out;
  float* edge_out = node_out + (size_t)NN * 128;

  int nb_scan = (NN + 255) / 256;  // 391

  hipMemsetAsync(counts, 0, (size_t)NN * 4, stream);

  k_detect<<<1, 64, 0, stream>>>(edge_index, flag);
  k_convert_hist<<<(2 * EE + 255) / 256, 256, 0, stream>>>(edge_index, flag, idx32, counts);
  k_gemm_node<<<(NN + 63) / 64, 512, 0, stream>>>(point_attr, W, att_src, att_dst,
                                                  xb, a_src, a_dst, NN);
  k_blocksum<<<nb_scan, 256, 0, stream>>>(counts, partials, NN);
  k_scanpartials<<<1, 512, 0, stream>>>(partials, nb_scan);
  k_scanfinal<<<nb_scan, 256, 0, stream>>>(counts, partials, offsets, cursor, NN);
  k_scatter<<<(EE + 255) / 256, 256, 0, stream>>>(edge_attr, W_edge, att_edge, srcp,
                                                  dstp, a_src, a_dst, cursor,
                                                  pair, alpha);
  k_megaagg<<<(NN + 7) / 8, 512, 0, stream>>>(offsets, pair, alpha, xb, bias,
                                              ln_node_g, ln_node_b, node_out, inv_arr);
  k_edgeout<<<(EE + 255) / 256, 256, 0, stream>>>(alpha, dstp, inv_arr, ln_edge_g,
                                                  ln_edge_b, edge_w, edge_b, edge_out);
}